// Round 2
// baseline (270.258 us; speedup 1.0000x reference)
//
#include <hip/hip_runtime.h>
#include <stdint.h>

// Keep IoU arithmetic bit-identical to an IEEE no-FMA reference:
#pragma clang fp contract(off)

#define BB   8
#define NN   2048
#define CC   32
#define WORDS 64           // uint32 words per 2048-bit row mask
#define NMS_THR 0.45f
#define PRE_THR 0.005f

// ---------------- Kernel A: per-image adjacency bitmask ----------------
// grid (64, 8): block (x,b) handles rows [x*32, x*32+32) of image b.
// Lane l owns output word l of each row (bits for columns [32l, 32l+32)).
// Division-free hot path: two-sided guard around thr*union, exact IEEE div
// only on borderline lanes (rel. window 2e-5) -> bit-identical decisions.
__global__ __launch_bounds__(256) void adj_kernel(const float* __restrict__ bbs,
                                                  uint32_t* __restrict__ adj) {
    __shared__ float4 sbox[NN];  // 32 KB
    const int b = blockIdx.y;
    const int t = threadIdx.x;
    const float4* bp = (const float4*)bbs + (size_t)b * NN;
    for (int i = t; i < NN; i += 256) sbox[i] = bp[i];
    __syncthreads();

    const int wave = t >> 6, lane = t & 63;
    const int row0 = blockIdx.x * 32 + wave * 8;
    uint32_t* const ap = adj + (size_t)b * NN * WORDS + lane;

    for (int g = 0; g < 2; ++g) {
        const int r0 = row0 + g * 4;
        float ax1[4], ay1[4], ax2[4], ay2[4], areaA[4];
#pragma unroll
        for (int r = 0; r < 4; ++r) {
            float4 A = sbox[r0 + r];          // uniform broadcast read
            ax1[r] = A.x; ay1[r] = A.y; ax2[r] = A.z; ay2[r] = A.w;
            areaA[r] = (A.z - A.x) * (A.w - A.y);
        }
        uint32_t m0 = 0, m1 = 0, m2 = 0, m3 = 0;
#pragma unroll
        for (int j = 0; j < 32; ++j) {
            const int jj  = (j + lane) & 31;       // rotate to spread LDS banks
            const int col = lane * 32 + jj;
            float4 Bx = sbox[col];
            float areaB = (Bx.z - Bx.x) * (Bx.w - Bx.y);
#pragma unroll
            for (int r = 0; r < 4; ++r) {
                float ltx = fmaxf(ax1[r], Bx.x), lty = fmaxf(ay1[r], Bx.y);
                float rbx = fminf(ax2[r], Bx.z), rby = fminf(ay2[r], Bx.w);
                float w  = fmaxf(rbx - ltx, 0.0f);
                float h  = fmaxf(rby - lty, 0.0f);
                float inter = w * h;
                float uni   = (areaA[r] + areaB) - inter;
                float unim  = fmaxf(uni, 1e-12f);
                float p     = NMS_THR * unim;
                bool def = inter > p * (1.0f + 1e-5f);
                bool bor = (inter > p * (1.0f - 1e-5f)) && !def;
                bool adjb;
                if (__any((int)bor)) {
                    float q = inter / unim;       // exact IEEE div, rare path
                    adjb = def || (bor && (q > NMS_THR));
                } else {
                    adjb = def;
                }
                adjb = adjb && (col != r0 + r);   // clear diagonal
                uint32_t bit = adjb ? (1u << jj) : 0u;
                if      (r == 0) m0 |= bit;
                else if (r == 1) m1 |= bit;
                else if (r == 2) m2 |= bit;
                else             m3 |= bit;
            }
        }
        ap[(size_t)(r0 + 0) * WORDS] = m0;
        ap[(size_t)(r0 + 1) * WORDS] = m1;
        ap[(size_t)(r0 + 2) * WORDS] = m2;
        ap[(size_t)(r0 + 3) * WORDS] = m3;
    }
}

// ---------------- Kernel B: per-(b,c) sort + blocked greedy NMS ----------------
// grid 256 (= B*C), 256 threads. Scan processes 32 ranks per step:
//   parallel row fetch + bpermute-extracted 32x32 sub-adjacency + scalar resolve.
__global__ __launch_bounds__(256) void nms_kernel(const float* __restrict__ conf,
                                                  const uint32_t* __restrict__ adj,
                                                  float* __restrict__ out) {
    __shared__ unsigned long long keys[NN];  // 16 KB
    __shared__ uint32_t ordv[NN];            // 8 KB: idx | (nonzero<<16)
    __shared__ uint32_t Sarr[WORDS];         // final suppressed mask
    const int bc = blockIdx.x;
    const int b  = bc >> 5;
    const int c  = bc & 31;
    const int t  = threadIdx.x;
    const float* cf = conf + ((size_t)b * CC + c) * NN;

    // Keys: (bits(thresholded conf) << 32) | (2047 - i).
    // Descending sort on key == JAX stable argsort(-conf) (ties: lower index first).
    for (int i = t; i < NN; i += 256) {
        float v  = cf[i];
        float vt = (v > PRE_THR) ? v : 0.0f;
        keys[i] = ((unsigned long long)__float_as_uint(vt) << 32) | (uint32_t)(NN - 1 - i);
    }
    __syncthreads();

    // Bitonic sort, descending (keys unique).
    for (unsigned k = 2; k <= NN; k <<= 1) {
        for (unsigned j = k >> 1; j > 0; j >>= 1) {
            for (unsigned p = t; p < NN / 2; p += 256) {
                unsigned i  = ((p & ~(j - 1)) << 1) | (p & (j - 1));
                unsigned ij = i | j;
                unsigned long long a = keys[i], d = keys[ij];
                bool up = ((i & k) == 0);
                if (up ? (a < d) : (a > d)) { keys[i] = d; keys[ij] = a; }
            }
            __syncthreads();
        }
    }

    for (int r = t; r < NN; r += 256) {
        unsigned long long kk = keys[r];
        uint32_t idx = (uint32_t)(NN - 1) - (uint32_t)(kk & 0xffffffffu);
        uint32_t nz  = ((uint32_t)(kk >> 32) != 0u) ? 0x10000u : 0u;
        ordv[r] = idx | nz;
    }
    __syncthreads();

    // ---- Blocked greedy scan, wave 0 only. S word l lives in lane l. ----
    if (t < 64) {
        const int lane = t;
        const uint32_t* const rowptr = adj + (size_t)b * NN * WORDS + lane;
        uint32_t S = 0;

        // Issue the 32 row loads for block `blk` into rb[] (per-lane word `lane`).
        auto issue_loads = [&](int blk, uint32_t (&rb)[32]) {
#pragma unroll
            for (int d = 0; d < 32; ++d) {
                uint32_t u = ordv[blk * 32 + d];           // uniform broadcast LDS read
                rb[d] = rowptr[(size_t)(u & 0xffffu) * WORDS];
            }
        };

        auto do_block = [&](int blk, uint32_t (&rb)[32], uint32_t (&rbN)[32]) {
            // Per-lane rank data for this block (lanes 32-63 duplicate 0-31).
            int vo   = (int)ordv[blk * 32 + (lane & 31)];
            int idx  = vo & 0xffff;
            int wq   = ((idx >> 5) & 63) << 2;             // byte addr for bpermute
            int bpos = idx & 31;

            if (blk < 63) issue_loads(blk + 1, rbN);       // prefetch next block

            // alive0: not already suppressed, conf nonzero.
            int Sw = __builtin_amdgcn_ds_bpermute(wq, (int)S);
            bool a0 = (((vo >> 16) & 1) != 0) && (((Sw >> bpos) & 1) == 0);
            uint32_t alive = (uint32_t)__ballot((int)a0);  // low 32 bits = ranks 0..31

            // Sub-adjacency extraction fused with serial resolve.
#pragma unroll
            for (int d = 0; d < 32; ++d) {
                int pm = __builtin_amdgcn_ds_bpermute(wq, (int)rb[d]);
                uint32_t Md = (uint32_t)__ballot(((pm >> bpos) & 1) != 0);
                uint32_t mk = Md & (0xFFFFFFFEu << d);     // only later ranks
                alive = (alive & (1u << d)) ? (alive & ~mk) : alive;
            }

            // OR rows of surviving (active) boxes into S.
#pragma unroll
            for (int d = 0; d < 32; ++d) {
                uint32_t sel = (alive & (1u << d)) ? 0xFFFFFFFFu : 0u;
                S |= rb[d] & sel;
            }
        };

        uint32_t rbA[32], rbB[32];
        issue_loads(0, rbA);
        for (int blk = 0; blk < 64; blk += 2) {
            do_block(blk,     rbA, rbB);
            do_block(blk + 1, rbB, rbA);
        }
        Sarr[lane] = S;
    }
    __syncthreads();

    float* op = out + ((size_t)b * CC + c) * NN;
    for (int i = t; i < NN; i += 256) {
        float v = cf[i];
        bool sup = (Sarr[i >> 5] >> (i & 31)) & 1u;
        op[i] = (v > PRE_THR && !sup) ? v : 0.0f;
    }
}

extern "C" void kernel_launch(void* const* d_in, const int* in_sizes, int n_in,
                              void* d_out, int out_size, void* d_ws, size_t ws_size,
                              hipStream_t stream) {
    const float* bbs  = (const float*)d_in[0];   // [8,2048,4]
    const float* conf = (const float*)d_in[1];   // [8,32,2048]
    float* out = (float*)d_out;                  // [8,32,2048]
    uint32_t* adj = (uint32_t*)d_ws;             // 8*2048*64*4 = 4 MB

    const size_t need = (size_t)BB * NN * WORDS * sizeof(uint32_t);
    if (ws_size < need) return;

    adj_kernel<<<dim3(64, BB), 256, 0, stream>>>(bbs, adj);
    nms_kernel<<<BB * CC, 256, 0, stream>>>(conf, adj, out);
}

// Round 3
// 220.894 us; speedup vs baseline: 1.2235x; 1.2235x over previous
//
#include <hip/hip_runtime.h>
#include <stdint.h>

// Keep IoU arithmetic bit-identical to an IEEE no-FMA reference:
#pragma clang fp contract(off)

#define BB   8
#define NN   2048
#define CC   32
#define WORDS 64           // uint32 words per 2048-bit row mask
#define NBLK 64            // rank blocks of 32
#define NMS_THR 0.45f
#define PRE_THR 0.005f
#define PADI(i) ((((i) >> 5) * 33) + ((i) & 31))   // padded SoA index, bank-conflict-free

// ---------------- Kernel A: per-image adjacency bitmask ----------------
// grid (64, 8): block (x,b) -> rows [x*32, x*32+32) of image b; wave w -> 8 rows.
// Lane l owns output word l (columns [32l, 32l+32)). Branch-free IEEE division.
__global__ __launch_bounds__(256) void adj_kernel(const float* __restrict__ bbs,
                                                  uint32_t* __restrict__ adj) {
    __shared__ float sx1[2112], sy1[2112], sx2[2112], sy2[2112];  // 33-stride pad
    const int b = blockIdx.y;
    const int t = threadIdx.x;
    const float4* bp = (const float4*)bbs + (size_t)b * NN;
    for (int i = t; i < NN; i += 256) {
        float4 v = bp[i];
        int p = PADI(i);
        sx1[p] = v.x; sy1[p] = v.y; sx2[p] = v.z; sy2[p] = v.w;
    }
    __syncthreads();

    const int wave = t >> 6, lane = t & 63;
    const int row0 = blockIdx.x * 32 + wave * 8;

    float ax1[8], ay1[8], ax2[8], ay2[8], areaA[8];
#pragma unroll
    for (int r = 0; r < 8; ++r) {
        int p = PADI(row0 + r);
        ax1[r] = sx1[p]; ay1[r] = sy1[p]; ax2[r] = sx2[p]; ay2[r] = sy2[p];
        areaA[r] = (ax2[r] - ax1[r]) * (ay2[r] - ay1[r]);
    }
    uint32_t w[8] = {0, 0, 0, 0, 0, 0, 0, 0};
    for (int j = 0; j < 32; ++j) {
        int p = lane * 33 + j;                     // bank (lane+j)%32: 2-way = free
        float bx1 = sx1[p], by1 = sy1[p], bx2 = sx2[p], by2 = sy2[p];
        float areaB = (bx2 - bx1) * (by2 - by1);
#pragma unroll
        for (int r = 0; r < 8; ++r) {
            float ltx = fmaxf(ax1[r], bx1), lty = fmaxf(ay1[r], by1);
            float rbx = fminf(ax2[r], bx2), rby = fminf(ay2[r], by2);
            float ww = fmaxf(rbx - ltx, 0.0f);
            float hh = fmaxf(rby - lty, 0.0f);
            float inter = ww * hh;
            float uni = (areaA[r] + areaB) - inter;
            float q = inter / fmaxf(uni, 1e-12f);  // exact IEEE div, branch-free
            if (q > NMS_THR) w[r] |= (1u << j);
        }
    }
#pragma unroll
    for (int r = 0; r < 8; ++r) {
        int row = row0 + r;
        uint32_t dmask = (lane == (row >> 5)) ? ~(1u << (row & 31)) : 0xFFFFFFFFu;
        adj[((size_t)b * NN + row) * WORDS + lane] = w[r] & dmask;
    }
}

// ---------------- Kernel B: per-(b,c) sort + blocked greedy NMS ----------------
// Phase A: bitonic sort (all threads). Phase B: extract all 64 32x32 rank-space
// sub-adjacency matrices into LDS (all 4 waves, S-independent, latency-hidden).
// Phase C: wave-0 serial scan: per block 1 bpermute + ballot + SALU resolve +
// masked OR of prefetched rows.
__global__ __launch_bounds__(256) void nms_kernel(const float* __restrict__ conf,
                                                  const uint32_t* __restrict__ adj,
                                                  float* __restrict__ out) {
    __shared__ unsigned long long keys[NN];  // 16KB
    __shared__ uint32_t ordv[NN];            // 8KB: idx | (nonzero<<16)
    __shared__ uint32_t Mlds[NBLK * 32];     // 8KB: rank-space sub-adjacency rows
    __shared__ uint32_t Sarr[WORDS];
    const int bc = blockIdx.x;
    const int b  = bc >> 5;
    const int c  = bc & 31;
    const int t  = threadIdx.x;
    const float* cf = conf + ((size_t)b * CC + c) * NN;
    const uint32_t* const abase = adj + (size_t)b * NN * WORDS;

    // ---- Phase A: keys + bitonic sort + ordv ----
    for (int i = t; i < NN; i += 256) {
        float v  = cf[i];
        float vt = (v > PRE_THR) ? v : 0.0f;
        keys[i] = ((unsigned long long)__float_as_uint(vt) << 32) | (uint32_t)(NN - 1 - i);
    }
    __syncthreads();
    for (unsigned k = 2; k <= NN; k <<= 1) {
        for (unsigned j = k >> 1; j > 0; j >>= 1) {
            for (unsigned p = t; p < NN / 2; p += 256) {
                unsigned i  = ((p & ~(j - 1)) << 1) | (p & (j - 1));
                unsigned ij = i | j;
                unsigned long long a = keys[i], d = keys[ij];
                bool up = ((i & k) == 0);
                if (up ? (a < d) : (a > d)) { keys[i] = d; keys[ij] = a; }
            }
            __syncthreads();
        }
    }
    for (int r = t; r < NN; r += 256) {
        unsigned long long kk = keys[r];
        uint32_t idx = (uint32_t)(NN - 1) - (uint32_t)(kk & 0xffffffffu);
        uint32_t nz  = ((uint32_t)(kk >> 32) != 0u) ? 0x10000u : 0u;
        ordv[r] = idx | nz;
    }
    __syncthreads();

    // ---- Phase B: sub-adjacency extraction (4 waves x 16 blocks) ----
    {
        const int wid = t >> 6, lane = t & 63, e = lane & 31, h = lane >> 5;
        for (int blk = wid * 16; blk < wid * 16 + 16; ++blk) {
            uint32_t ue = ordv[blk * 32 + e];
            int widx = (int)((ue & 0xffffu) >> 5);
            int bpos = (int)(ue & 31u);
            uint32_t vM = 0;
#pragma unroll
            for (int half = 0; half < 2; ++half) {
                uint32_t wbuf[8];
#pragma unroll
                for (int k = 0; k < 8; ++k) {
                    int d = half * 16 + k * 2 + h;
                    uint32_t ud = ordv[blk * 32 + d] & 0xffffu;
                    wbuf[k] = abase[(size_t)ud * WORDS + widx];   // row-uniform gather
                }
#pragma unroll
                for (int k = 0; k < 8; ++k) {
                    int d0 = half * 16 + k * 2;
                    unsigned long long bal = __ballot(((wbuf[k] >> bpos) & 1u) != 0u);
                    vM = (lane == d0    ) ? (uint32_t)bal         : vM;
                    vM = (lane == d0 + 1) ? (uint32_t)(bal >> 32) : vM;
                }
            }
            if (lane < 32) Mlds[blk * 32 + lane] = vM;
        }
    }
    __syncthreads();

    // ---- Phase C: wave-0 serial scan over 64 blocks ----
    if (t < 64) {
        const int lane = t;
        const uint32_t* const rowp = abase + lane;   // lane l reads word l of any row
        uint32_t S = 0;
        uint32_t rbA[32], rbB[32];
        uint32_t u_c, m_c, u_n, m_n;

        u_c = ordv[lane & 31];
        m_c = Mlds[lane & 31];
#pragma unroll
        for (int d = 0; d < 32; ++d) {
            int ud = __builtin_amdgcn_readlane((int)u_c, d) & 0xffff;
            rbA[d] = rowp[(size_t)ud * WORDS];
        }

        auto do_block = [&](int blk, uint32_t (&rbC)[32], uint32_t (&rbN)[32]) {
            u_n = 0; m_n = 0;
            if (blk < 63) {
                u_n = ordv[(blk + 1) * 32 + (lane & 31)];
                m_n = Mlds[(blk + 1) * 32 + (lane & 31)];
#pragma unroll
                for (int d = 0; d < 32; ++d) {
                    int ud = __builtin_amdgcn_readlane((int)u_n, d) & 0xffff;
                    rbN[d] = rowp[(size_t)ud * WORDS];
                }
            }
            // alive0: not suppressed by S, conf nonzero
            int wq  = (int)(((u_c & 0xffffu) >> 5) << 2);
            int bpv = (int)(u_c & 31u);
            int pm  = __builtin_amdgcn_ds_bpermute(wq, (int)S);
            bool a0 = (((u_c >> 16) & 1u) != 0u) && (((pm >> bpv) & 1) == 0);
            uint32_t alive = (uint32_t)__ballot((int)a0);
            // within-block greedy resolve (scalar, rows from prefetched M)
#pragma unroll
            for (int d = 0; d < 32; ++d) {
                uint32_t rowd = (uint32_t)__builtin_amdgcn_readlane((int)m_c, d);
                uint32_t mk = rowd & (0xFFFFFFFEu << d);
                alive = (alive & (1u << d)) ? (alive & ~mk) : alive;
            }
            // OR survivors' rows into S
            uint32_t acc = 0;
#pragma unroll
            for (int d = 0; d < 32; ++d)
                acc |= (alive & (1u << d)) ? rbC[d] : 0u;
            S |= acc;
            u_c = u_n; m_c = m_n;
        };

        for (int blk = 0; blk < 64; blk += 2) {
            do_block(blk,     rbA, rbB);
            do_block(blk + 1, rbB, rbA);
        }
        Sarr[lane] = S;
    }
    __syncthreads();

    float* op = out + ((size_t)b * CC + c) * NN;
    for (int i = t; i < NN; i += 256) {
        float v = cf[i];
        bool sup = (Sarr[i >> 5] >> (i & 31)) & 1u;
        op[i] = (v > PRE_THR && !sup) ? v : 0.0f;
    }
}

extern "C" void kernel_launch(void* const* d_in, const int* in_sizes, int n_in,
                              void* d_out, int out_size, void* d_ws, size_t ws_size,
                              hipStream_t stream) {
    const float* bbs  = (const float*)d_in[0];   // [8,2048,4]
    const float* conf = (const float*)d_in[1];   // [8,32,2048]
    float* out = (float*)d_out;                  // [8,32,2048]
    uint32_t* adj = (uint32_t*)d_ws;             // 8*2048*64*4 = 4 MB

    const size_t need = (size_t)BB * NN * WORDS * sizeof(uint32_t);
    if (ws_size < need) return;

    adj_kernel<<<dim3(64, BB), 256, 0, stream>>>(bbs, adj);
    nms_kernel<<<BB * CC, 256, 0, stream>>>(conf, adj, out);
}